// Round 13
// baseline (230.508 us; speedup 1.0000x reference)
//
#include <hip/hip_runtime.h>
#include <hip/hip_bf16.h>
#include <cstddef>
#include <cstdint>

// Problem dims
constexpr int Nn = 4096;
constexpr int Ss = 128;
constexpr int Ff = 128;
constexpr int Dd = 256;
constexpr float EPSV = 1e-8f;

// d_out layout (floats): h_o [N*D], C_new [N*S*F], k [N*F], r [N*F]
constexpr size_t HO_OFF = 0;
constexpr size_t C_OFF  = (size_t)Nn * Dd;
constexpr size_t K_OFF  = C_OFF + (size_t)Nn * Ss * Ff;
constexpr size_t R_OFF  = K_OFF + (size_t)Nn * Ff;

typedef __attribute__((ext_vector_type(4))) float f4v;
typedef __attribute__((ext_vector_type(8))) short bh8;
typedef __attribute__((ext_vector_type(4))) short bh4;

// bf16 weight pack offsets in ws (units: shorts)
constexpr int WK_O  = 0;        // Wk   128x256
constexpr int WHH_O = 32768;    // Whh  768x256
constexpr int WIH_O = 229376;   // Wih  768x128
constexpr int WEV_O = 327680;   // [We;Wv] 256x256
constexpr int W_TOT = 393216;

__device__ __forceinline__ float sigmf(float x) { return 1.0f / (1.0f + __expf(-x)); }

__device__ __forceinline__ short f2bf(float x) {
    __hip_bfloat16 h = __float2bfloat16(x);   // RNE
    return *reinterpret_cast<short*>(&h);
}

// XOR swizzle: spread 16B k-slots of row r across banks. Row strides 512B / 256B.
__device__ __forceinline__ int swzH(int row, int kb) { return row * 512 + (kb ^ ((row & 7) << 4)); }
__device__ __forceinline__ int swzR(int row, int kb) { return row * 256 + (kb ^ ((row & 7) << 4)); }

__device__ __forceinline__ f4v mfma16(bh8 a, bh8 b, f4v c) {
    return __builtin_amdgcn_mfma_f32_16x16x32_bf16(a, b, c, 0, 0, 0);
}

// ---------------------------------------------------------------------------
// Prep: convert all weights to bf16, packed row-major into ws.
// ---------------------------------------------------------------------------
__global__ __launch_bounds__(256) void prep_weights(
    const float* __restrict__ Wk, const float* __restrict__ Whh,
    const float* __restrict__ Wih, const float* __restrict__ We,
    const float* __restrict__ Wv, short* __restrict__ out)
{
    int id = blockIdx.x * 256 + threadIdx.x;   // grid covers W_TOT exactly
    float v;
    if      (id < WHH_O) v = Wk[id - WK_O];
    else if (id < WIH_O) v = Whh[id - WHH_O];
    else if (id < WEV_O) v = Wih[id - WIH_O];
    else if (id < WEV_O + 32768) v = We[id - WEV_O];
    else v = Wv[id - WEV_O - 32768];
    out[id] = f2bf(v);
}

// ---------------------------------------------------------------------------
// Mega kernel v2: 1024 blocks x 256 threads; block = 4 rows, wave w = row w.
// 4x the independent blocks of R5-R12 (2/CU -> 4/CU co-resident, 6 allowed by
// 24KB LDS) so barrier-phased blocks overlap memory and compute across blocks.
//  P0 load h (fp32 + swizzled bf16, zero pads)
//  P1 k = h@Wk^T + bk          [MFMA, 2 col-passes]
//  P2 attention TILED (R12): per 16-row tile: A scores (4 lanes/row, 2 shfls),
//     B r-partials re-reading the L1-hot tile. Fixed-shift p=exp(x-beta).
//  P3 gh/gi MFMAs in 4 (dp,cs)-passes, gates in regs -> h_o
//  P5 [e|v] = sig/lin(h_o@[We;Wv]^T)  [MFMA, 4 col-passes]
//  P6 C_new = C*(1-w*e)+w*v (C re-read L3-hot), NT stores
// ---------------------------------------------------------------------------
__global__ __launch_bounds__(256, 2) void mega_kernel(
    const float* __restrict__ C, const float* __restrict__ h_prev,
    const short* __restrict__ WB,
    const float* __restrict__ Wb, const float* __restrict__ bb,
    const float* __restrict__ bk, const float* __restrict__ bhh,
    const float* __restrict__ bih, const float* __restrict__ be,
    const float* __restrict__ bv,
    float* __restrict__ ho, float* __restrict__ Cnew,
    float* __restrict__ kout, float* __restrict__ rout)
{
    __shared__ float sH[4][256];                  // h_prev fp32            4 KB
    __shared__ __align__(16) short sHb[16 * 256]; // h/h_o bf16 swizzled    8 KB
    __shared__ __align__(16) short sRb[16 * 128]; // r bf16 swizzled        4 KB
    __shared__ float sK[4][128];                  //                        2 KB
    __shared__ float sSc[4][128];                 // p per (row,s)          2 KB
    __shared__ float sEV[4][256];                 // e | v                  4 KB
                                                  // total 24 KB -> 6 blk/CU

    const int t  = threadIdx.x;
    const int l  = t & 63;
    const int wv = t >> 6;          // wave = row, 0..3
    const int nb = blockIdx.x * 4;
    char* hb = (char*)sHb;
    char* rb = (char*)sRb;

    const short* WkB  = WB + WK_O;
    const short* WhhB = WB + WHH_O;
    const short* WihB = WB + WIH_O;
    const short* WevB = WB + WEV_O;

    // ---- P0: load 4 h rows, build swizzled bf16 copy, zero pad rows
    {
        const int f = t * 4, row = f >> 8, col = f & 255;   // row 0..3
        float4 hv = *(const float4*)(h_prev + (size_t)(nb + row) * Dd + col);
        *(float4*)&sH[row][col] = hv;
        bh4 hb4 = { f2bf(hv.x), f2bf(hv.y), f2bf(hv.z), f2bf(hv.w) };
        *(bh4*)(hb + swzH(row, col * 2)) = hb4;
        // sHb rows 4..15 (bytes 2048..8191 = 6144 B)
        *(int4*)(hb + 2048 + t * 16) = int4{0, 0, 0, 0};   // 2048..6143
        *(int64_t*)(hb + 6144 + t * 8) = 0;                // 6144..8191
        // sRb rows 4..15 (bytes 1024..4095 = 3072 B)
        *(int64_t*)(rb + 1024 + t * 8) = 0;                // 1024..3071
        *(int*)(rb + 3072 + t * 4) = 0;                    // 3072..4095
    }
    __syncthreads();

    const int fr = l & 15, kq = l >> 4;

    // ---- P1: k = h @ Wk^T + bk  (2 col-passes of 64)
    {
#pragma unroll
        for (int i = 0; i < 2; ++i) {
            const int colg = i * 64 + wv * 16 + fr;
            f4v acc = {0.f, 0.f, 0.f, 0.f};
#pragma unroll
            for (int kc = 0; kc < 8; ++kc) {
                bh8 a = *(const bh8*)(hb + swzH(fr, kc * 64 + kq * 16));
                bh8 b = *(const bh8*)(WkB + (size_t)colg * 256 + kc * 32 + kq * 8);
                acc = mfma16(a, b, acc);
            }
            if (kq == 0) {   // rows 0..3 valid
                const float bs = bk[colg];
#pragma unroll
                for (int rg = 0; rg < 4; ++rg) {
                    float x = acc[rg] + bs;
                    sK[rg][colg] = x;
                    kout[(size_t)(nb + rg) * Ff + colg] = x;
                }
            }
        }
    }
    __syncthreads();

    // ---- P2: attention, tiled A/B (tile = 16 s-rows = 8KB, L1/L2-resident)
    float invL_r = 0.0f;   // live to P6
    {
        const float* Cn = C + (size_t)(nb + wv) * (Ss * Ff);

        float kv0 = sK[wv][l], kv1 = sK[wv][64 + l];
        float ks = kv0 * kv0 + kv1 * kv1;
#pragma unroll
        for (int o = 32; o > 0; o >>= 1) ks += __shfl_xor(ks, o);
        const float knorm = fmaxf(sqrtf(ks), EPSV);

        float4 hv = *(const float4*)&sH[wv][l * 4];
        float4 wb4 = *(const float4*)(Wb + l * 4);
        float bp = hv.x * wb4.x + hv.y * wb4.y + hv.z * wb4.z + hv.w * wb4.w;
#pragma unroll
        for (int o = 32; o > 0; o >>= 1) bp += __shfl_xor(bp, o);
        bp += bb[0];
        const float beta = ((bp > 20.0f) ? bp : log1pf(__expf(bp))) + 1.0f;
        const float bOkn = beta / knorm;

        const int qrow = l >> 2;            // phase A: row within tile
        const int subf = l & 3;             // phase A: f-quarter
        const int half = l >> 5, fl = l & 31, f4 = fl * 4;
        float lsum = 0.0f;
        f4v racc = {0.f, 0.f, 0.f, 0.f};

#pragma unroll 1
        for (int tile = 0; tile < 8; ++tile) {
            const int s0 = tile * 16;
            // --- phase A: scores for rows s0..s0+15 (4 lanes per row)
            const float* rowp = Cn + (size_t)(s0 + qrow) * Ff + subf * 32;
            float d = 0.f, q = 0.f;
#pragma unroll
            for (int fc = 0; fc < 8; ++fc) {
                const f4v c4 = *(const f4v*)(rowp + fc * 4);
                const f4v k4 = *(const f4v*)&sK[wv][subf * 32 + fc * 4];
                d += c4.x * k4.x + c4.y * k4.y + c4.z * k4.z + c4.w * k4.w;
                q += c4.x * c4.x + c4.y * c4.y + c4.z * c4.z + c4.w * c4.w;
            }
            d += __shfl_xor(d, 1); d += __shfl_xor(d, 2);
            q += __shfl_xor(q, 1); q += __shfl_xor(q, 2);
            const float x = d / fmaxf(sqrtf(q), EPSV) * bOkn;   // <= beta
            const float p = __expf(x - beta);
            if (subf == 0) sSc[wv][s0 + qrow] = p;
            lsum += p;                       // each row counted 4x; fix later
            // --- phase B: r partial over the same tile (cache-hot), f-parallel
#pragma unroll
            for (int j = 0; j < 8; ++j) {
                const int s = s0 + j * 2 + half;
                const float pp = sSc[wv][s];
                const f4v c4 = *(const f4v*)(Cn + (size_t)s * Ff + f4);
                racc += pp * c4;
            }
        }
#pragma unroll
        for (int o = 32; o > 0; o >>= 1) lsum += __shfl_xor(lsum, o);
        const float iL = 4.0f / lsum;        // rows counted 4x in lsum
        invL_r = iL;

        f4v r2;
        r2.x = __shfl_xor(racc.x, 32); r2.y = __shfl_xor(racc.y, 32);
        r2.z = __shfl_xor(racc.z, 32); r2.w = __shfl_xor(racc.w, 32);
        f4v r4 = (racc + r2) * iL;
        if (half == 0) {
            *(f4v*)(rout + (size_t)(nb + wv) * Ff + f4) = r4;
            bh4 rb4 = { f2bf(r4.x), f2bf(r4.y), f2bf(r4.z), f2bf(r4.w) };
            *(bh4*)(rb + swzR(wv, f4 * 2)) = rb4;
        }
    }
    __syncthreads();

    // ---- P3: gh/gi MFMAs + gates in registers, 4 (dp,cs)-passes
    {
        float hoReg[2][2][4];
#pragma unroll
        for (int dp = 0; dp < 2; ++dp) {
#pragma unroll
            for (int cs = 0; cs < 2; ++cs) {
                f4v aG[3], aI[3];
#pragma unroll
                for (int g3 = 0; g3 < 3; ++g3) {
                    const int colg = (g3 * 2 + dp) * 128 + cs * 64 + wv * 16 + fr;
                    f4v g = {0.f, 0.f, 0.f, 0.f}, ii = {0.f, 0.f, 0.f, 0.f};
#pragma unroll
                    for (int kc = 0; kc < 8; ++kc) {
                        bh8 a = *(const bh8*)(hb + swzH(fr, kc * 64 + kq * 16));
                        bh8 b = *(const bh8*)(WhhB + (size_t)colg * 256 + kc * 32 + kq * 8);
                        g = mfma16(a, b, g);
                    }
#pragma unroll
                    for (int kc = 0; kc < 4; ++kc) {
                        bh8 a = *(const bh8*)(rb + swzR(fr, kc * 64 + kq * 16));
                        bh8 b = *(const bh8*)(WihB + (size_t)colg * 128 + kc * 32 + kq * 8);
                        ii = mfma16(a, b, ii);
                    }
                    aG[g3] = g; aI[g3] = ii;
                }
                if (kq == 0) {
                    const int d = dp * 128 + cs * 64 + wv * 16 + fr;
                    const float br  = bhh[d] + bih[d];
                    const float bz  = bhh[256 + d] + bih[256 + d];
                    const float bhn = bhh[512 + d];
                    const float bin = bih[512 + d];
#pragma unroll
                    for (int rg = 0; rg < 4; ++rg) {
                        const float rgt = sigmf(aG[0][rg] + aI[0][rg] + br);
                        const float z   = sigmf(aG[1][rg] + aI[1][rg] + bz);
                        const float nn  = tanhf(aI[2][rg] + bin + rgt * (aG[2][rg] + bhn));
                        const float hp  = sH[rg][d];
                        hoReg[dp][cs][rg] = (1.0f - z) * nn + z * hp;
                    }
                }
            }
        }
        __syncthreads();   // all waves done reading sHb(h) as A-frags
        if (kq == 0) {
#pragma unroll
            for (int dp = 0; dp < 2; ++dp)
#pragma unroll
                for (int cs = 0; cs < 2; ++cs) {
                    const int d = dp * 128 + cs * 64 + wv * 16 + fr;
#pragma unroll
                    for (int rg = 0; rg < 4; ++rg) {
                        const float o = hoReg[dp][cs][rg];
                        ho[(size_t)(nb + rg) * Dd + d] = o;
                        *(short*)(hb + rg * 512 + ((d * 2) ^ ((rg & 7) << 4))) = f2bf(o);
                    }
                }
        }
    }
    __syncthreads();

    // ---- P5: [e|v] = h_o @ [We;Wv]^T (+sigmoid on e), 4 col-passes
    {
#pragma unroll
        for (int i = 0; i < 4; ++i) {
            const int colg = i * 64 + wv * 16 + fr;
            f4v acc = {0.f, 0.f, 0.f, 0.f};
#pragma unroll
            for (int kc = 0; kc < 8; ++kc) {
                bh8 a = *(const bh8*)(hb + swzH(fr, kc * 64 + kq * 16));
                bh8 b = *(const bh8*)(WevB + (size_t)colg * 256 + kc * 32 + kq * 8);
                acc = mfma16(a, b, acc);
            }
            if (kq == 0) {
                const float bs = (colg < 128) ? be[colg] : bv[colg - 128];
#pragma unroll
                for (int rg = 0; rg < 4; ++rg) {
                    float x = acc[rg] + bs;
                    if (colg < 128) x = sigmf(x);
                    sEV[rg][colg] = x;
                }
            }
        }
    }
    __syncthreads();

    // ---- P6: C_new = C*(1-w*e)+w*v (C re-read L2/L3-hot), NT stores
    {
        const int half = l >> 5, fl = l & 31, f4 = fl * 4;
        const float* Cn = C    + (size_t)(nb + wv) * (Ss * Ff);
        float*       Co = Cnew + (size_t)(nb + wv) * (Ss * Ff);
        const f4v e4 = *(const f4v*)&sEV[wv][f4];
        const f4v v4 = *(const f4v*)&sEV[wv][128 + f4];
        const float iL = invL_r;

#pragma unroll 4
        for (int k = 0; k < 64; ++k) {
            const int s = k * 2 + half;
            const f4v c4 = *(const f4v*)(Cn + (size_t)s * Ff + f4);
            const float wsc = sSc[wv][s] * iL;
            f4v o = c4 * (1.0f - wsc * e4) + wsc * v4;
            __builtin_nontemporal_store(o, (f4v*)(Co + (size_t)s * Ff + f4));
        }
    }
}

// ---------------------------------------------------------------------------
extern "C" void kernel_launch(void* const* d_in, const int* in_sizes, int n_in,
                              void* d_out, int out_size, void* d_ws, size_t ws_size,
                              hipStream_t stream)
{
    const float* h_prev = (const float*)d_in[0];
    const float* C      = (const float*)d_in[1];
    const float* Wk     = (const float*)d_in[2];
    const float* bk     = (const float*)d_in[3];
    const float* Wb     = (const float*)d_in[4];
    const float* bb     = (const float*)d_in[5];
    const float* We     = (const float*)d_in[6];
    const float* be     = (const float*)d_in[7];
    const float* Wv     = (const float*)d_in[8];
    const float* bv     = (const float*)d_in[9];
    const float* Wih    = (const float*)d_in[10];
    const float* Whh    = (const float*)d_in[11];
    const float* bih    = (const float*)d_in[12];
    const float* bhh    = (const float*)d_in[13];

    float* out  = (float*)d_out;
    float* ho   = out + HO_OFF;
    float* Cnew = out + C_OFF;
    float* kbuf = out + K_OFF;
    float* rbuf = out + R_OFF;

    short* wsB = (short*)d_ws;

    prep_weights<<<W_TOT / 256, 256, 0, stream>>>(Wk, Whh, Wih, We, Wv, wsB);

    mega_kernel<<<Nn / 4, 256, 0, stream>>>(
        C, h_prev, wsB, Wb, bb, bk, bhh, bih, be, bv,
        ho, Cnew, kbuf, rbuf);
}